// Round 8
// baseline (250.017 us; speedup 1.0000x reference)
//
#include <hip/hip_runtime.h>
#include <stdint.h>

// Leaky LIF SNN forward, x/spk: [T=128, B*N=262144] fp32.
//   reset_t = H(mem_{t-1} - 1); mem_t = 0.5*mem_{t-1} + x_t - reset_t; spk_t = H(mem_t - 1)
//
// R7 inference: pure strided read runs ~2.2 TB/s even with no write stream
// (pack ~60us). Model: 2^20-stride freezes bank/page bits per agent ->
// same-bank row-miss storm on every DRAM access. R8 decisive test: PRIME the
// L3 with a sequential sweep of x (134 MB < 256 MB L3; harness poison evicts
// ~65 MB/iter) so pack's strided reads are 100% cache hits, bypassing DRAM
// pages entirely. prime -> pack (bit-planes, 4 MB ws) -> expand (sequential
// 131 MB write at fill rate).

#define T_STEPS 128
#define NWORDS 4          // 128 bits per neuron
#define D 24              // pack rolling prefetch depth

// K0: sequential sweep of x -> L3 resident. Dummy per-thread sums written
// into the plane area of ws; pack overwrites all 4 MB afterwards
// (stream-ordered), so this is safe scratch.
__global__ __launch_bounds__(256) void snn_prime(const float4* __restrict__ x,
                                                 float* __restrict__ ws,
                                                 int n4tot) {
    const int tid = blockIdx.x * blockDim.x + threadIdx.x;
    const int stride = gridDim.x * blockDim.x;
    float4 acc = make_float4(0.f, 0.f, 0.f, 0.f);
    for (int i = tid; i < n4tot; i += stride) {
        const float4 v = x[i];
        acc.x += v.x; acc.y += v.y; acc.z += v.z; acc.w += v.w;
    }
    ws[tid] = acc.x + acc.y + acc.z + acc.w;   // keep the loads live
}

// K1: per-neuron recurrence, rolling register ring, spikes packed to 4 uint32.
__global__ __launch_bounds__(256) void snn_pack(const float* __restrict__ x,
                                                uint32_t* __restrict__ ws,  // [NWORDS][n]
                                                int n) {
    const int idx = blockIdx.x * blockDim.x + threadIdx.x;
    if (idx >= n) return;
    const float* xp = x + idx;

    float buf[D];
    float mem = 0.0f;
    uint32_t w0 = 0, w1 = 0, w2 = 0, w3 = 0;

#pragma unroll
    for (int u = 0; u < D; ++u) buf[u] = xp[(size_t)u * n];

#pragma unroll
    for (int t = 0; t < T_STEPS; ++t) {
        const float v = buf[t % D];                 // static index after unroll
        if (t + D < T_STEPS) buf[t % D] = xp[(size_t)(t + D) * n];
        mem = 0.5f * mem + v - (mem > 1.0f ? 1.0f : 0.0f);
        const uint32_t bit = (mem > 1.0f) ? 1u : 0u;
        if (t < 32)       w0 |= bit << (t & 31);
        else if (t < 64)  w1 |= bit << (t & 31);
        else if (t < 96)  w2 |= bit << (t & 31);
        else              w3 |= bit << (t & 31);
    }
    ws[(size_t)0 * n + idx] = w0;
    ws[(size_t)1 * n + idx] = w1;
    ws[(size_t)2 * n + idx] = w2;
    ws[(size_t)3 * n + idx] = w3;
}

// K2: expand bit-planes to fp32; each block writes a contiguous 256 KB span.
__global__ __launch_bounds__(256) void snn_expand(const uint32_t* __restrict__ ws,
                                                  float4* __restrict__ out,
                                                  int n) {
    const int t = blockIdx.x >> 2;
    const int q = blockIdx.x & 3;
    const int n4 = n >> 2;              // float4s per row (65536)
    const int span4 = n4 >> 2;          // float4s per quarter (16384)
    const int sh = t & 31;

    const uint32_t* plane = ws + (size_t)(t >> 5) * n;
    const uint4* wp4 = (const uint4*)plane + (size_t)q * span4;
    float4* op = out + (size_t)t * n4 + (size_t)q * span4;

    for (int i = threadIdx.x; i < span4; i += 256) {
        const uint4 w = wp4[i];
        float4 o;
        o.x = (float)((w.x >> sh) & 1u);
        o.y = (float)((w.y >> sh) & 1u);
        o.z = (float)((w.z >> sh) & 1u);
        o.w = (float)((w.w >> sh) & 1u);
        op[i] = o;
    }
}

// Fallback (ws too small): R3-style fused kernel, known-good ~81 us.
__global__ __launch_bounds__(256) void snn_fused(const float* __restrict__ x,
                                                 float* __restrict__ out,
                                                 int n) {
    const int idx = blockIdx.x * blockDim.x + threadIdx.x;
    if (idx >= n) return;
    const float* xp = x + idx;
    float* op = out + idx;

    float buf[D];
    float mem = 0.0f;
#pragma unroll
    for (int u = 0; u < D; ++u) buf[u] = xp[(size_t)u * n];
#pragma unroll
    for (int t = 0; t < T_STEPS; ++t) {
        const float v = buf[t % D];
        if (t + D < T_STEPS) buf[t % D] = xp[(size_t)(t + D) * n];
        mem = 0.5f * mem + v - (mem > 1.0f ? 1.0f : 0.0f);
        const float spk = (mem > 1.0f) ? 1.0f : 0.0f;
        __builtin_nontemporal_store(spk, op + (size_t)t * n);
    }
}

extern "C" void kernel_launch(void* const* d_in, const int* in_sizes, int n_in,
                              void* d_out, int out_size, void* d_ws, size_t ws_size,
                              hipStream_t stream) {
    const float* x = (const float*)d_in[0];
    const int total = in_sizes[0];          // T*B*N = 128*64*4096
    const int n = total / T_STEPS;          // 262144 neurons

    const size_t ws_needed = (size_t)NWORDS * (size_t)n * sizeof(uint32_t); // 4 MB

    if (ws_size >= ws_needed) {
        uint32_t* ws = (uint32_t*)d_ws;
        // prime: 2048 blocks x 256 thr, grid-stride over 8.4M float4s
        snn_prime<<<2048, 256, 0, stream>>>((const float4*)x, (float*)d_ws, total / 4);
        snn_pack<<<(n + 255) / 256, 256, 0, stream>>>(x, ws, n);
        snn_expand<<<T_STEPS * 4, 256, 0, stream>>>(ws, (float4*)d_out, n);
    } else {
        snn_fused<<<(n + 255) / 256, 256, 0, stream>>>(x, (float*)d_out, n);
    }
}